// Round 7
// baseline (98.048 us; speedup 1.0000x reference)
//
#include <hip/hip_runtime.h>
#include <math.h>

#define HW 512
#define NB 16
#define TX 64           // tile width
#define TY 64           // tile height
#define LDSW 72         // TX + 8 (4-col halo each side, float4-aligned)
#define LDSH 70         // TY + 6
#define N_PIX (NB * HW * HW)   // 4194304
#define NBLK (8 * 8 * NB)      // 1024 phase-1 blocks

// Force a float into an SGPR (uniform across wave).
__device__ __forceinline__ float sgpr_f(float v) {
    return __uint_as_float(__builtin_amdgcn_readfirstlane(__float_as_uint(v)));
}

// Phase 1: 64x64 tile per block; thread = 1 column x 16 rows.
// Writes avg, dif, ratio = x/s; per-block partial sum(s^2) to partials[flat].
__global__ __launch_bounds__(256, 4) void li_phase1(
    const float* __restrict__ x, const float* __restrict__ kw,
    float* __restrict__ out_ratio, float* __restrict__ out_avg,
    float* __restrict__ out_dif, float* __restrict__ partials)
{
    __shared__ float tile[LDSH * LDSW];   // 20160 B
    __shared__ float wsum[4];

    const int tid = threadIdx.x;
    const int bx = blockIdx.x, by = blockIdx.y, b = blockIdx.z;
    const int x0 = bx * TX, y0 = by * TY;
    const float* xb = x + (size_t)b * (HW * HW);

    // 49 weights pinned to SGPRs.
    float w[49];
#pragma unroll
    for (int i = 0; i < 49; i++) w[i] = sgpr_f(kw[i]);

    // Stage 70 x 72 tile with zero halo, float4 granularity.
    for (int idx = tid; idx < LDSH * (LDSW / 4); idx += 256) {
        int r = idx / (LDSW / 4);
        int c4 = idx - r * (LDSW / 4);
        int gy = y0 - 3 + r;
        int gx = x0 - 4 + c4 * 4;
        float4 v = make_float4(0.f, 0.f, 0.f, 0.f);
        if ((unsigned)gy < HW && (unsigned)gx < HW)
            v = *(const float4*)(xb + gy * HW + gx);
        *(float4*)&tile[r * LDSW + c4 * 4] = v;
    }
    __syncthreads();

    const int tx  = tid & 63;         // column within tile
    const int ty0 = (tid >> 6) * 16;  // first of 16 output rows

    float cen[16];
#pragma unroll
    for (int p = 0; p < 16; p++)
        cen[p] = tile[(ty0 + p + 3) * LDSW + tx + 4];

    float dif[16], bsum[16];
#pragma unroll
    for (int p = 0; p < 16; p++) { dif[p] = 0.f; bsum[p] = 0.f; }

    // Stream 22 window rows; row r feeds pixels p with di = r-p in [0,7).
#pragma unroll
    for (int r = 0; r < 22; r++) {
        float v[7];
#pragma unroll
        for (int dj = 0; dj < 7; dj++)
            v[dj] = tile[(ty0 + r) * LDSW + tx + 1 + dj];

        float rs = ((v[0] + v[1]) + (v[2] + v[3])) + ((v[4] + v[5]) + v[6]);
#pragma unroll
        for (int p = 0; p < 16; p++) {
            const int di = r - p;
            if (di >= 0 && di < 7) {
                bsum[p] += rs;
#pragma unroll
                for (int dj = 0; dj < 7; dj++) {
                    if (di == 3 && dj == 3) continue;  // relu(cen-cen)==0, exact skip
                    dif[p] = fmaf(w[di * 7 + dj], fmaxf(v[dj] - cen[p], 0.f), dif[p]);
                }
            }
        }
    }

    const size_t base = (size_t)b * (HW * HW) + (size_t)(y0 + ty0) * HW + x0 + tx;
    float ss = 0.f;
#pragma unroll
    for (int p = 0; p < 16; p++) {
        float avg = __expf(-bsum[p] * (1.0f / 49.0f));
        float d = dif[p];
        float sp = 0.1f * avg + 0.9f * d;        // > 0 always
        size_t gi = base + (size_t)p * HW;
        __builtin_nontemporal_store(avg, out_avg + gi);   // never re-read
        __builtin_nontemporal_store(d,   out_dif + gi);
        out_ratio[gi] = cen[p] * __builtin_amdgcn_rcpf(sp);
        ss = fmaf(sp, sp, ss);
    }

#pragma unroll
    for (int off = 32; off > 0; off >>= 1)
        ss += __shfl_down(ss, off, 64);
    if ((tid & 63) == 0) wsum[tid >> 6] = ss;
    __syncthreads();
    if (tid == 0)
        partials[bx + 8 * (by + 8 * b)] = (wsum[0] + wsum[1]) + (wsum[2] + wsum[3]);
}

// Phase 2 (reduce fused): each block sums the 1024 partials itself (L2-resident,
// 4 KB), then masks its 4096-element slice in place: mask = (ratio > 1/sqrt(ss)).
__global__ __launch_bounds__(256) void li_phase2(
    const float* __restrict__ partials, float* __restrict__ io)
{
    __shared__ float wsum[4];
    __shared__ float s_inv;
    const int tid = threadIdx.x;

    float s = 0.f;
#pragma unroll
    for (int i = 0; i < NBLK / 256; i++)
        s += partials[tid + i * 256];
#pragma unroll
    for (int off = 32; off > 0; off >>= 1)
        s += __shfl_down(s, off, 64);
    if ((tid & 63) == 0) wsum[tid >> 6] = s;
    __syncthreads();
    if (tid == 0)
        s_inv = 1.0f / sqrtf((wsum[0] + wsum[1]) + (wsum[2] + wsum[3]));
    __syncthreads();

    const float inv = s_inv;
    const int base = blockIdx.x * 4096 + tid * 4;
#pragma unroll
    for (int k = 0; k < 4; k++) {
        const int i = base + k * 1024;
        float4 r = *(const float4*)(io + i);
        float4 m;
        m.x = (r.x > inv) ? 1.f : 0.f;
        m.y = (r.y > inv) ? 1.f : 0.f;
        m.z = (r.z > inv) ? 1.f : 0.f;
        m.w = (r.w > inv) ? 1.f : 0.f;
        *(float4*)(io + i) = m;
    }
}

extern "C" void kernel_launch(void* const* d_in, const int* in_sizes, int n_in,
                              void* d_out, int out_size, void* d_ws, size_t ws_size,
                              hipStream_t stream) {
    const float* x  = (const float*)d_in[0];
    const float* kw = (const float*)d_in[1];
    float* out   = (float*)d_out;
    float* ratio = out;                       // becomes mask after phase 2
    float* avg   = out + N_PIX;
    float* dif   = out + 2 * (size_t)N_PIX;
    float* ws    = (float*)d_ws;              // [0,NBLK): partials (fully written)

    dim3 g(HW / TX, HW / TY, NB);   // 8 x 8 x 16 = 1024 blocks
    li_phase1<<<g, 256, 0, stream>>>(x, kw, ratio, avg, dif, ws);
    li_phase2<<<N_PIX / 4096, 256, 0, stream>>>(ws, ratio);
}

// Round 8
// 95.178 us; speedup vs baseline: 1.0301x; 1.0301x over previous
//
#include <hip/hip_runtime.h>
#include <math.h>

#define HW 512
#define NB 16
#define TX 64           // tile width
#define TY 64           // tile height
#define LDSW 72         // TX + 8 (4-col halo each side, float4-aligned)
#define LDSH 70         // TY + 6
#define N_PIX (NB * HW * HW)   // 4194304
#define NBLK (8 * 8 * NB)      // 1024 phase-1 blocks

// Force a float into an SGPR (uniform across wave).
__device__ __forceinline__ float sgpr_f(float v) {
    return __uint_as_float(__builtin_amdgcn_readfirstlane(__float_as_uint(v)));
}

// Phase 1: 64x64 tile per block; thread = 1 column x 16 rows.
// dif via identity: sum w*relu(v-c) = sum w*max(v,c) - c*sum(w)  (2 ops/tap).
__global__ __launch_bounds__(256, 4) void li_phase1(
    const float* __restrict__ x, const float* __restrict__ kw,
    float* __restrict__ out_ratio, float* __restrict__ out_avg,
    float* __restrict__ out_dif, float* __restrict__ partials)
{
    __shared__ float tile[LDSH * LDSW];   // 20160 B
    __shared__ float wsum[4];

    const int tid = threadIdx.x;
    const int bx = blockIdx.x, by = blockIdx.y, b = blockIdx.z;
    const int x0 = bx * TX, y0 = by * TY;
    const float* xb = x + (size_t)b * (HW * HW);

    // 49 weights pinned to SGPRs; W = sum of all weights (center weight is 0).
    float w[49];
    float W = 0.f;
#pragma unroll
    for (int i = 0; i < 49; i++) { w[i] = sgpr_f(kw[i]); W += w[i]; }

    // Stage 70 x 72 tile with zero halo, float4 granularity.
    for (int idx = tid; idx < LDSH * (LDSW / 4); idx += 256) {
        int r = idx / (LDSW / 4);
        int c4 = idx - r * (LDSW / 4);
        int gy = y0 - 3 + r;
        int gx = x0 - 4 + c4 * 4;
        float4 v = make_float4(0.f, 0.f, 0.f, 0.f);
        if ((unsigned)gy < HW && (unsigned)gx < HW)
            v = *(const float4*)(xb + gy * HW + gx);
        *(float4*)&tile[r * LDSW + c4 * 4] = v;
    }
    __syncthreads();

    const int tx  = tid & 63;         // column within tile
    const int ty0 = (tid >> 6) * 16;  // first of 16 output rows

    float cen[16];
#pragma unroll
    for (int p = 0; p < 16; p++)
        cen[p] = tile[(ty0 + p + 3) * LDSW + tx + 4];

    float dif[16], bsum[16];
#pragma unroll
    for (int p = 0; p < 16; p++) { dif[p] = 0.f; bsum[p] = 0.f; }

    // Software-pipelined row stream: prefetch row r+1 while consuming row r.
    float vc[7], vn[7];
#pragma unroll
    for (int dj = 0; dj < 7; dj++)
        vc[dj] = tile[ty0 * LDSW + tx + 1 + dj];

#pragma unroll
    for (int r = 0; r < 22; r++) {
        if (r < 21) {
#pragma unroll
            for (int dj = 0; dj < 7; dj++)
                vn[dj] = tile[(ty0 + r + 1) * LDSW + tx + 1 + dj];
        }

        float rs = ((vc[0] + vc[1]) + (vc[2] + vc[3])) + ((vc[4] + vc[5]) + vc[6]);
#pragma unroll
        for (int p = 0; p < 16; p++) {
            const int di = r - p;
            if (di >= 0 && di < 7) {
                bsum[p] += rs;
#pragma unroll
                for (int dj = 0; dj < 7; dj++) {
                    if (di == 3 && dj == 3) continue;   // center weight == 0
                    dif[p] = fmaf(w[di * 7 + dj], fmaxf(vc[dj], cen[p]), dif[p]);
                }
            }
        }

#pragma unroll
        for (int dj = 0; dj < 7; dj++) vc[dj] = vn[dj];
    }

    const size_t base = (size_t)b * (HW * HW) + (size_t)(y0 + ty0) * HW + x0 + tx;
    float ss = 0.f;
#pragma unroll
    for (int p = 0; p < 16; p++) {
        float avg = __expf(-bsum[p] * (1.0f / 49.0f));
        float d = fmaf(-W, cen[p], dif[p]);     // subtract c*sum(w)
        float sp = 0.1f * avg + 0.9f * d;        // > 0 always
        size_t gi = base + (size_t)p * HW;
        __builtin_nontemporal_store(avg, out_avg + gi);   // never re-read
        __builtin_nontemporal_store(d,   out_dif + gi);
        out_ratio[gi] = cen[p] * __builtin_amdgcn_rcpf(sp);
        ss = fmaf(sp, sp, ss);
    }

#pragma unroll
    for (int off = 32; off > 0; off >>= 1)
        ss += __shfl_down(ss, off, 64);
    if ((tid & 63) == 0) wsum[tid >> 6] = ss;
    __syncthreads();
    if (tid == 0)
        partials[bx + 8 * (by + 8 * b)] = (wsum[0] + wsum[1]) + (wsum[2] + wsum[3]);
}

// Phase 2 (reduce fused): each block sums the 1024 partials itself (L2-resident,
// 4 KB), then masks its 4096-element slice in place: mask = (ratio > 1/sqrt(ss)).
__global__ __launch_bounds__(256) void li_phase2(
    const float* __restrict__ partials, float* __restrict__ io)
{
    __shared__ float wsum[4];
    __shared__ float s_inv;
    const int tid = threadIdx.x;

    float s = 0.f;
#pragma unroll
    for (int i = 0; i < NBLK / 256; i++)
        s += partials[tid + i * 256];
#pragma unroll
    for (int off = 32; off > 0; off >>= 1)
        s += __shfl_down(s, off, 64);
    if ((tid & 63) == 0) wsum[tid >> 6] = s;
    __syncthreads();
    if (tid == 0)
        s_inv = 1.0f / sqrtf((wsum[0] + wsum[1]) + (wsum[2] + wsum[3]));
    __syncthreads();

    const float inv = s_inv;
    const int base = blockIdx.x * 4096 + tid * 4;
#pragma unroll
    for (int k = 0; k < 4; k++) {
        const int i = base + k * 1024;
        float4 r = *(const float4*)(io + i);
        float4 m;
        m.x = (r.x > inv) ? 1.f : 0.f;
        m.y = (r.y > inv) ? 1.f : 0.f;
        m.z = (r.z > inv) ? 1.f : 0.f;
        m.w = (r.w > inv) ? 1.f : 0.f;
        *(float4*)(io + i) = m;
    }
}

extern "C" void kernel_launch(void* const* d_in, const int* in_sizes, int n_in,
                              void* d_out, int out_size, void* d_ws, size_t ws_size,
                              hipStream_t stream) {
    const float* x  = (const float*)d_in[0];
    const float* kw = (const float*)d_in[1];
    float* out   = (float*)d_out;
    float* ratio = out;                       // becomes mask after phase 2
    float* avg   = out + N_PIX;
    float* dif   = out + 2 * (size_t)N_PIX;
    float* ws    = (float*)d_ws;              // [0,NBLK): partials (fully written)

    dim3 g(HW / TX, HW / TY, NB);   // 8 x 8 x 16 = 1024 blocks
    li_phase1<<<g, 256, 0, stream>>>(x, kw, ratio, avg, dif, ws);
    li_phase2<<<N_PIX / 4096, 256, 0, stream>>>(ws, ratio);
}